// Round 4
// baseline (86.738 us; speedup 1.0000x reference)
//
#include <hip/hip_runtime.h>
#include <math.h>

// NoisyTopKRouter via f16 2-limb (Markidis) 3-pass MFMA, fully fused.
// Round 4: BM=32 (grid 512, 2 blocks/CU), B-fragments direct global->VGPR
// (wt L2-resident), x-only LDS staging, raw s_barrier (no vmcnt drain),
// 2-deep x prefetch + 1-deep B prefetch in named registers (unroll-2).

typedef _Float16 f16;
typedef _Float16 f16x2 __attribute__((ext_vector_type(2)));
typedef _Float16 f16x8 __attribute__((ext_vector_type(8)));
typedef float    f32x4 __attribute__((ext_vector_type(4)));

#define NEMBD 2048
#define NEXP  64
#define BM    32
#define BK    32
#define NCH   64              // 2048 / 32
#define XP    40              // padded LDS row stride (f16); 80B = 16B-aligned rows
#define WSCALE 64.0f
#define INV_WSCALE 0.015625f

union F4H8 { float4 f; f16x8 h; };

// ---------- kernel 0: W -> transposed, x64-scaled f16 limbs ----------
// wt layout per limb: [chunk 64][n 128][k 32] f16 (n: 0..63 route, 64..127 noise)
__global__ __launch_bounds__(256) void build_wt(
    const float* __restrict__ Wr, const float* __restrict__ Wn,
    f16* __restrict__ wt_hi, f16* __restrict__ wt_lo)
{
    __shared__ float ws[BK][129];
    const int c = blockIdx.x, t = threadIdx.x;
    const int k0 = c * BK;
    {
        const int k  = t >> 3;
        const int n8 = (t & 7) << 3;
        const float* s0 = Wr + (size_t)(k0 + k) * NEXP + n8;
        const float* s1 = Wn + (size_t)(k0 + k) * NEXP + n8;
        #pragma unroll
        for (int j = 0; j < 8; ++j) ws[k][n8 + j] = s0[j];
        #pragma unroll
        for (int j = 0; j < 8; ++j) ws[k][64 + n8 + j] = s1[j];
    }
    __syncthreads();
    {
        const int n  = t >> 1;           // 0..127
        const int kh = (t & 1) << 4;     // 0 or 16
        f16x8 hv0, hv1, lv0, lv1;
        #pragma unroll
        for (int j = 0; j < 8; ++j) {
            const float v = ws[kh + j][n] * WSCALE;
            const f16 h = (f16)v;
            hv0[j] = h; lv0[j] = (f16)(v - (float)h);
        }
        #pragma unroll
        for (int j = 0; j < 8; ++j) {
            const float v = ws[kh + 8 + j][n] * WSCALE;
            const f16 h = (f16)v;
            hv1[j] = h; lv1[j] = (f16)(v - (float)h);
        }
        const size_t base = ((size_t)c * 128 + n) * 32 + kh;
        *(f16x8*)(wt_hi + base)     = hv0;
        *(f16x8*)(wt_hi + base + 8) = hv1;
        *(f16x8*)(wt_lo + base)     = lv0;
        *(f16x8*)(wt_lo + base + 8) = lv1;
    }
}

// ---------- helpers ----------
__device__ __forceinline__ void wsplit2(float a, float b, f16x2& hi, f16x2& lo) {
    const f16 h0 = (f16)a, h1 = (f16)b;
    hi = (f16x2){h0, h1};
    lo = (f16x2){(f16)(a - (float)h0), (f16)(b - (float)h1)};
}

__device__ __forceinline__ void loadB(const f16* wt_hi, const f16* wt_lo,
    int c, int boff0, int boff1,
    f16x8& bh0, f16x8& bh1, f16x8& bl0, f16x8& bl1)
{
    const size_t cb = (size_t)c * 4096;
    F4H8 u0, u1, u2, u3;
    u0.f = *(const float4*)(wt_hi + cb + boff0);
    u1.f = *(const float4*)(wt_hi + cb + boff1);
    u2.f = *(const float4*)(wt_lo + cb + boff0);
    u3.f = *(const float4*)(wt_lo + cb + boff1);
    bh0 = u0.h; bh1 = u1.h; bl0 = u2.h; bl1 = u3.h;
}

// one K-chunk iteration; barrier keeps prefetches in flight (no vmcnt drain)
__device__ __forceinline__ void step(
    int c, bool doX, bool doB, bool doW,
    const float* xsrc, const f16* wt_hi, const f16* wt_lo,
    int boff0, int boff1, int aoff, int xwoff,
    const f16* XHr, const f16* XLr, f16* XHw, f16* XLw,
    float2& xsI, const float2& xsW,
    f16x8& biH0, f16x8& biH1, f16x8& biL0, f16x8& biL1,
    const f16x8& buH0, const f16x8& buH1, const f16x8& buL0, const f16x8& buL1,
    f32x4& acc0, f32x4& acc1)
{
    if (doX) xsI = *(const float2*)(xsrc + (c + 2) * BK);         // x(c+2) -> regs
    if (doB) loadB(wt_hi, wt_lo, c + 1, boff0, boff1, biH0, biH1, biL0, biL1); // B(c+1)
    const f16x8 ah = *(const f16x8*)(XHr + aoff);
    const f16x8 al = *(const f16x8*)(XLr + aoff);
    acc0 = __builtin_amdgcn_mfma_f32_16x16x32_f16(ah, buH0, acc0, 0, 0, 0);
    acc0 = __builtin_amdgcn_mfma_f32_16x16x32_f16(al, buH0, acc0, 0, 0, 0);
    acc0 = __builtin_amdgcn_mfma_f32_16x16x32_f16(ah, buL0, acc0, 0, 0, 0);
    acc1 = __builtin_amdgcn_mfma_f32_16x16x32_f16(ah, buH1, acc1, 0, 0, 0);
    acc1 = __builtin_amdgcn_mfma_f32_16x16x32_f16(al, buH1, acc1, 0, 0, 0);
    acc1 = __builtin_amdgcn_mfma_f32_16x16x32_f16(ah, buL1, acc1, 0, 0, 0);
    if (doW) {                                                     // write x(c+1)
        f16x2 hi, lo;
        wsplit2(xsW.x, xsW.y, hi, lo);
        *(f16x2*)(XHw + xwoff) = hi;
        *(f16x2*)(XLw + xwoff) = lo;
    }
    asm volatile("s_waitcnt lgkmcnt(0)" ::: "memory");  // ds ops done; vmem stays in flight
    __builtin_amdgcn_s_barrier();
    asm volatile("" ::: "memory");
}

// ---------- kernel 1: fused MFMA router ----------
// grid T/32, 512 threads = 8 waves; wave w: rows (w&1)*16, cols (w>>1)*32
__global__ __launch_bounds__(512, 4) void router_fused2(
    const float* __restrict__ x, const float* __restrict__ eps,
    const f16* __restrict__ wt_hi, const f16* __restrict__ wt_lo,
    const float* __restrict__ br, const float* __restrict__ bn,
    float* __restrict__ out_r, float* __restrict__ out_idx)
{
    __shared__ __align__(16) float smem[4352];          // 17408 B
    f16* XH0 = (f16*)smem;                               // [32][XP] buf0
    f16* XH1 = XH0 + 1280;                               // buf1
    f16* XL0 = XH0 + 2560;
    f16* XL1 = XH0 + 3840;
    float* LG = smem;                                    // [128][33] overlay (epilogue)
    float* TK = smem + 128 * 33;                         // [4][32]

    const int tid  = threadIdx.x;
    const int lane = tid & 63;
    const int w    = tid >> 6;
    const int wr   = w & 1, wc = w >> 1;
    const int m0   = blockIdx.x * BM;

    // x staging: thread -> (row, k-pair)
    const int sxr = tid >> 4;                 // 0..31
    const int sxk = (tid & 15) << 1;          // 0..30
    const float* xsrc = x + (size_t)(m0 + sxr) * NEMBD + sxk;
    const int xwoff = sxr * XP + sxk;

    // A fragment (rows of x)
    const int arow = wr * 16 + (lane & 15);
    const int kgrp = (lane >> 4) << 3;
    const int aoff = arow * XP + kgrp;

    // B fragment (cols of wt), direct global
    const int bcol  = wc * 32 + (lane & 15);
    const int boff0 = bcol * 32 + kgrp;
    const int boff1 = (bcol + 16) * 32 + kgrp;

    f32x4 acc0 = {0.f, 0.f, 0.f, 0.f}, acc1 = {0.f, 0.f, 0.f, 0.f};
    float2 xs0, xs1;
    f16x8 b0h0, b0h1, b0l0, b0l1, b1h0, b1h1, b1l0, b1l1;

    // prologue: x(0)->buf0; x(1)->xs1; B(0)->b1*
    {
        const float2 x0 = *(const float2*)(xsrc);
        f16x2 hi, lo;
        wsplit2(x0.x, x0.y, hi, lo);
        *(f16x2*)(XH0 + xwoff) = hi;
        *(f16x2*)(XL0 + xwoff) = lo;
        xs1 = *(const float2*)(xsrc + BK);
        loadB(wt_hi, wt_lo, 0, boff0, boff1, b1h0, b1h1, b1l0, b1l1);
        asm volatile("s_waitcnt lgkmcnt(0)" ::: "memory");
        __builtin_amdgcn_s_barrier();
        asm volatile("" ::: "memory");
    }

    // steady state: iters 0..61 (unroll-2, guard-free)
    for (int c = 0; c < NCH - 2; c += 2) {
        step(c,     true, true, true, xsrc, wt_hi, wt_lo, boff0, boff1, aoff, xwoff,
             XH0, XL0, XH1, XL1, xs0, xs1,
             b0h0, b0h1, b0l0, b0l1, b1h0, b1h1, b1l0, b1l1, acc0, acc1);
        step(c + 1, true, true, true, xsrc, wt_hi, wt_lo, boff0, boff1, aoff, xwoff,
             XH1, XL1, XH0, XL0, xs1, xs0,
             b1h0, b1h1, b1l0, b1l1, b0h0, b0h1, b0l0, b0l1, acc0, acc1);
    }
    // iter 62: issue B(63), write x(63), no new x
    step(62, false, true, true, xsrc, wt_hi, wt_lo, boff0, boff1, aoff, xwoff,
         XH0, XL0, XH1, XL1, xs0, xs1,
         b0h0, b0h1, b0l0, b0l1, b1h0, b1h1, b1l0, b1l1, acc0, acc1);
    // iter 63: compute only
    step(63, false, false, false, xsrc, wt_hi, wt_lo, boff0, boff1, aoff, xwoff,
         XH1, XL1, XH0, XL0, xs1, xs0,
         b1h0, b1h1, b1l0, b1l1, b0h0, b0h1, b0l0, b0l1, acc0, acc1);

    // ---- epilogue: descale + bias, logits -> LDS overlay ----
    #pragma unroll
    for (int j = 0; j < 2; ++j) {
        const int col = wc * 32 + j * 16 + (lane & 15);
        const float bias = (col < NEXP) ? br[col] : bn[col - NEXP];
        const int tokb = wr * 16 + ((lane >> 4) << 2);
        const f32x4 a = j ? acc1 : acc0;
        #pragma unroll
        for (int r = 0; r < 4; ++r)
            LG[col * 33 + tokb + r] = a[r] * INV_WSCALE + bias;
    }
    __syncthreads();

    // ---- top-2: 2 lanes per token, each scans 32 experts, shfl merge ----
    if (tid < 64) {
        const int t = tid >> 1;
        const int h = tid & 1;
        const float* ep = eps + (size_t)(m0 + t) * NEXP;
        float v1 = -1e30f, v2 = -1e30f;
        int i1 = 0, i2 = 0;
        for (int j = 0; j < 32; ++j) {
            const int e = h * 32 + j;
            const float r  = LG[e * 33 + t];
            const float nr = LG[(NEXP + e) * 33 + t];
            const float sp = fmaxf(nr, 0.f) + log1pf(expf(-fabsf(nr)));
            const float noisy = fmaf(ep[e], sp, r);
            if (noisy > v1) { v2 = v1; i2 = i1; v1 = noisy; i1 = e; }
            else if (noisy > v2) { v2 = noisy; i2 = e; }
        }
        const float ov1 = __shfl_xor(v1, 1);
        const float ov2 = __shfl_xor(v2, 1);
        const int   oi1 = __shfl_xor(i1, 1);
        const int   oi2 = __shfl_xor(i2, 1);
        // a = lower-index half (experts 0..31), b = upper; ties prefer a
        float a1, a2, bb1, bb2; int ai1, ai2, bj1, bj2;
        if (h) { a1 = ov1; a2 = ov2; ai1 = oi1; ai2 = oi2; bb1 = v1; bb2 = v2; bj1 = i1; bj2 = i2; }
        else   { a1 = v1;  a2 = v2;  ai1 = i1;  ai2 = i2;  bb1 = ov1; bb2 = ov2; bj1 = oi1; bj2 = oi2; }
        float t1, t2; int ti1, ti2;
        if (bb1 > a1) {
            t1 = bb1; ti1 = bj1;
            if (a1 >= bb2) { t2 = a1; ti2 = ai1; } else { t2 = bb2; ti2 = bj2; }
        } else {
            t1 = a1; ti1 = ai1;
            if (bb1 > a2) { t2 = bb1; ti2 = bj1; } else { t2 = a2; ti2 = ai2; }
        }
        if (h == 0) {
            const float e2 = expf(t2 - t1);
            const float p1 = 1.f / (1.f + e2);
            TK[0 * 32 + t] = p1;
            TK[1 * 32 + t] = e2 * p1;
            TK[2 * 32 + t] = (float)ti1;
            TK[3 * 32 + t] = (float)ti2;
        }
    }
    __syncthreads();

    // ---- write r_out coalesced (4 floats/thread) ----
    {
        const int t  = tid >> 4;             // 0..31
        const int c4 = (tid & 15) << 2;      // 0..60
        const float p1 = TK[t], p2 = TK[32 + t];
        const int i1 = (int)TK[64 + t], i2 = (int)TK[96 + t];
        float buf[4];
        #pragma unroll
        for (int jj = 0; jj < 4; ++jj) {
            const int e = c4 + jj;
            buf[jj] = (e == i1) ? p1 : (e == i2) ? p2 : 0.f;
        }
        *(float4*)(out_r + (size_t)(m0 + t) * NEXP + c4) = *(float4*)buf;
    }
    if (tid < BM) {
        float2 v = make_float2(TK[64 + tid], TK[96 + tid]);
        *(float2*)(out_idx + (size_t)(m0 + tid) * 2) = v;
    }
}

// ---------- fallback: fused f32 kernel (insurance only) ----------
__global__ __launch_bounds__(256) void router_fused_f32(
    const float* __restrict__ x, const float* __restrict__ eps,
    const float* __restrict__ Wr, const float* __restrict__ br,
    const float* __restrict__ Wn, const float* __restrict__ bn,
    float* __restrict__ out_r, float* __restrict__ out_idx)
{
    __shared__ float xs[BK][64];
    __shared__ float ws2[BK][128];
    __shared__ float lg[128][64];
    __shared__ float tk[4][64];
    const int tid = threadIdx.x;
    const int tx = tid & 15, ty = tid >> 4;
    const int m0 = blockIdx.x * 64;
    float acc[4][8];
    #pragma unroll
    for (int i = 0; i < 4; ++i)
        #pragma unroll
        for (int j = 0; j < 8; ++j) acc[i][j] = 0.f;
    for (int kc = 0; kc < NEMBD; kc += BK) {
        {
            const int tm = tid >> 2, kk = (tid & 3) << 3;
            const float* src = x + (size_t)(m0 + tm) * NEMBD + kc + kk;
            const float4 a = *(const float4*)(src);
            const float4 b = *(const float4*)(src + 4);
            xs[kk+0][tm]=a.x; xs[kk+1][tm]=a.y; xs[kk+2][tm]=a.z; xs[kk+3][tm]=a.w;
            xs[kk+4][tm]=b.x; xs[kk+5][tm]=b.y; xs[kk+6][tm]=b.z; xs[kk+7][tm]=b.w;
        }
        {
            const int kr = tid >> 3, q = tid & 7;
            const float* src = (q < 4)
                ? (Wr + (size_t)(kc + kr) * NEXP + (q << 4))
                : (Wn + (size_t)(kc + kr) * NEXP + ((q - 4) << 4));
            float* dst = &ws2[kr][q << 4];
            #pragma unroll
            for (int j = 0; j < 16; ++j) dst[j] = src[j];
        }
        __syncthreads();
        #pragma unroll
        for (int k = 0; k < BK; ++k) {
            const float4 xv = *(const float4*)&xs[k][ty << 2];
            const float4 wa = *(const float4*)&ws2[k][tx << 3];
            const float4 wb = *(const float4*)&ws2[k][(tx << 3) + 4];
            const float xr[4] = {xv.x, xv.y, xv.z, xv.w};
            const float wcx[8] = {wa.x, wa.y, wa.z, wa.w, wb.x, wb.y, wb.z, wb.w};
            #pragma unroll
            for (int i = 0; i < 4; ++i)
                #pragma unroll
                for (int j = 0; j < 8; ++j)
                    acc[i][j] = fmaf(xr[i], wcx[j], acc[i][j]);
        }
        __syncthreads();
    }
    {
        const int n0 = tx << 3;
        #pragma unroll
        for (int j = 0; j < 8; ++j) {
            const int n = n0 + j;
            const float b = (n < NEXP) ? br[n] : bn[n - NEXP];
            #pragma unroll
            for (int i = 0; i < 4; ++i)
                lg[n][(ty << 2) + i] = acc[i][j] + b;
        }
    }
    __syncthreads();
    if (tid < 64) {
        const int t = tid;
        const float* ep = eps + (size_t)(m0 + t) * NEXP;
        float v1 = -1e30f, v2 = -1e30f; int i1 = 0, i2 = 0;
        for (int e = 0; e < NEXP; ++e) {
            const float r = lg[e][t], nr = lg[NEXP + e][t];
            const float sp = fmaxf(nr, 0.f) + log1pf(expf(-fabsf(nr)));
            const float noisy = fmaf(ep[e], sp, r);
            if (noisy > v1) { v2=v1; i2=i1; v1=noisy; i1=e; }
            else if (noisy > v2) { v2=noisy; i2=e; }
        }
        const float e2 = expf(v2 - v1);
        const float p1 = 1.f / (1.f + e2);
        tk[0][t]=p1; tk[1][t]=e2*p1; tk[2][t]=(float)i1; tk[3][t]=(float)i2;
    }
    __syncthreads();
    {
        const int t = tid >> 2, c = tid & 3;
        const float p1 = tk[0][t], p2 = tk[1][t];
        const int i1 = (int)tk[2][t], i2 = (int)tk[3][t];
        float buf[16];
        #pragma unroll
        for (int j = 0; j < 16; ++j) {
            const int e = (c << 4) + j;
            buf[j] = (e == i1) ? p1 : (e == i2) ? p2 : 0.f;
        }
        float* dst = out_r + (size_t)(m0 + t) * NEXP + (c << 4);
        *(float4*)(dst+0)=*(float4*)(buf+0); *(float4*)(dst+4)=*(float4*)(buf+4);
        *(float4*)(dst+8)=*(float4*)(buf+8); *(float4*)(dst+12)=*(float4*)(buf+12);
    }
    if (tid < 64) {
        float2 v = make_float2(tk[2][tid], tk[3][tid]);
        *(float2*)(out_idx + (size_t)(m0 + tid) * 2) = v;
    }
}

extern "C" void kernel_launch(void* const* d_in, const int* in_sizes, int n_in,
                              void* d_out, int out_size, void* d_ws, size_t ws_size,
                              hipStream_t stream) {
    const float* x  = (const float*)d_in[0];
    const float* ep = (const float*)d_in[1];
    const float* Wr = (const float*)d_in[2];
    const float* br = (const float*)d_in[3];
    const float* Wn = (const float*)d_in[4];
    const float* bn = (const float*)d_in[5];

    const int T = in_sizes[1] / NEXP;
    float* out_r   = (float*)d_out;
    float* out_idx = (float*)d_out + (size_t)T * NEXP;

    const size_t limb = (size_t)128 * NEMBD * sizeof(f16);   // 512 KB
    if (ws_size >= 2 * limb) {
        f16* wt_hi = (f16*)d_ws;
        f16* wt_lo = wt_hi + (size_t)128 * NEMBD;
        build_wt<<<NCH, 256, 0, stream>>>(Wr, Wn, wt_hi, wt_lo);
        router_fused2<<<T / BM, 512, 0, stream>>>(
            x, ep, wt_hi, wt_lo, br, bn, out_r, out_idx);
    } else {
        router_fused_f32<<<T / 64, 256, 0, stream>>>(
            x, ep, Wr, br, Wn, bn, out_r, out_idx);
    }
}